// Round 9
// baseline (489.780 us; speedup 1.0000x reference)
//
#include <hip/hip_runtime.h>

#define NV 300000
#define KT 9
#define NF 64
#define NBLK ((NV + 63) / 64)   // 4688 blocks of 64 rows

typedef __attribute__((ext_vector_type(8))) short bf16x8;
typedef __attribute__((ext_vector_type(4))) float f32x4;
typedef __attribute__((ext_vector_type(4))) float f4;
typedef __attribute__((ext_vector_type(4))) unsigned short u16x4;

// round-to-nearest-even f32 -> bf16 bits
__device__ __forceinline__ unsigned short f2bf(float f) {
    union { float f; unsigned int u; } a; a.f = f;
    unsigned int u = a.u;
    return (unsigned short)((u + 0x7FFFu + ((u >> 16) & 1u)) >> 16);
}

// prep: blocks 0..17 transpose+cvt weights (w[k][f][o] -> wt[k][o][f] bf16),
//       blocks 18..  convert relu(lv) -> bf16 (exact grid, one f4/thread)
__global__ void prep_kernel(const float* __restrict__ lv,
                            const float* __restrict__ w1,
                            const float* __restrict__ w2,
                            unsigned short* __restrict__ xbf0,
                            unsigned short* __restrict__ wt1,
                            unsigned short* __restrict__ wt2) {
    int b = blockIdx.x;
    if (b < 18) {
        const float* w = (b < 9) ? w1 : w2;
        unsigned short* wt = (b < 9) ? wt1 : wt2;
        int k = (b < 9) ? b : b - 9;
        for (int e = threadIdx.x; e < NF * NF; e += 256) {
            int o = e >> 6, f = e & 63;
            wt[(k * NF + o) * NF + f] = f2bf(w[(k * NF + f) * NF + o]);
        }
    } else {
        const int n4 = NV * NF / 4;   // 4,800,000
        int i = (b - 18) * 256 + threadIdx.x;
        if (i < n4) {
            f4 v = ((const f4*)lv)[i];
            u16x4 r;
            #pragma unroll
            for (int j = 0; j < 4; ++j) r[j] = f2bf(fmaxf(v[j], 0.f));
            ((u16x4*)xbf0)[i] = r;
        }
    }
}

// One lattice conv layer: out[n,o] = sum_k sum_f xin[nbr[n,k], f] * w[k][f][o] (+bias)
// LAYER==1: bfout = bf16(relu(conv + b))     (feeds next layer's gather)
// LAYER==2: fout  = conv + b + resid         (fp32 final output)
//
// BARRIER-FREE private-wave design: each of the 4 waves owns 16 rows x 64
// cols. A wave stages only its own 16-row tap tile (2 global_load_lds) into
// its private LDS slice and consumes it itself -> no inter-wave hazard, no
// s_barrier in the tap loop (only the initial nbs __syncthreads). Weight
// fragments are re-read per tap from the L2-hot 73.7 KB wt (8 x b128).
// Private per-wave vmcnt ledger per phase k:
//   issue w(k) x8, stage(k+1) x2, s_waitcnt vmcnt(2)
//   -> retires s(k) (oldest) + w(k); keeps s(k+1) in flight. Never drains.
// LDS: gA[2][4 waves][16][64] = 16 KiB + nbs 2.3 KiB -> 8 blocks/CU.
template<int LAYER>
__global__ __launch_bounds__(256, 8)
void conv_kernel(const unsigned short* __restrict__ xin,  // bf16 bits [NV][64]
                 const int* __restrict__ nbr,             // [NV][9]
                 const unsigned short* __restrict__ wt,   // bf16 [9][64][64], o-major
                 const float* __restrict__ bias,          // [64]
                 const float* __restrict__ resid,         // [NV][64] (LAYER==2)
                 unsigned short* __restrict__ bfout,      // LAYER==1
                 float* __restrict__ fout)                // LAYER==2
{
    __shared__ unsigned short gA[2][4][16][64];  // [buf][wave][row][col]
    __shared__ int nbs[576];                     // 64 rows x 9 taps

    const int tid  = threadIdx.x;
    const int lane = tid & 63;
    const int wv   = tid >> 6;               // wave 0..3 -> rows wv*16..+15
    const int base = blockIdx.x * 64;

    // neighbor tile -> LDS
    for (int e = tid; e < 576; e += 256) {
        long ge = (long)base * 9 + e;
        nbs[e] = (ge < (long)NV * 9) ? nbr[ge] : 0;
    }

    // bias for this lane's 4 col-blocks (loaded before the sync drain)
    float bv[4];
    #pragma unroll
    for (int n = 0; n < 4; ++n) bv[n] = bias[n * 16 + (lane & 15)];

    f32x4 acc[4];
    #pragma unroll
    for (int n = 0; n < 4; ++n) acc[n] = (f32x4){0.f, 0.f, 0.f, 0.f};

    // drains vmcnt to 0 (nbr + bias loads) and publishes nbs. The ONLY
    // barrier in the kernel — after this every wave is fully private and the
    // per-wave counted-vmcnt ledger below is exact.
    __syncthreads();

    // stage tap k into this wave's slice of buffer k&1.
    // load h covers rows wv*16 + h*8 .. +7; lane l: row16 = h*8 + (l>>3),
    // fetches global 16B-chunk (l&7)^(row16&7) into linear LDS slot
    // (row16, l&7)   [both-sides XOR swizzle, LDS dest linear].
    const int srow = lane >> 3;
    const int sj   = lane & 7;
    auto stage = [&](int k) {
        #pragma unroll
        for (int h = 0; h < 2; ++h) {
            const int row16 = h * 8 + srow;
            const int nb    = nbs[(wv * 16 + row16) * 9 + k];
            const int gcol  = sj ^ (row16 & 7);
            const unsigned short* src = xin + nb * 64 + gcol * 8;
            __builtin_amdgcn_global_load_lds(
                (const __attribute__((address_space(1))) unsigned int*)src,
                (__attribute__((address_space(3))) unsigned int*)&gA[k & 1][wv][h * 8][0],
                16, 0, 0);
        }
    };

    // B fragment for tap k, col-block n, k-half kk:
    // lane l reg j = w[k][kk*32 + (l>>4)*8 + j][n*16 + (l&15)]
    auto ldw = [&](int k, int n, int kk) {
        return *(const bf16x8*)&wt[(k * 64 + n * 16 + (lane & 15)) * 64 + kk * 32 + (lane >> 4) * 8];
    };

    // per-tap compute: 8 x ds_read_b128 (<=2-way bank alias, free) + 8 MFMA
    auto tap = [&](int k, bf16x8 (&bwk)[4][2]) {
        #pragma unroll
        for (int n = 0; n < 4; ++n) {
            #pragma unroll
            for (int kk = 0; kk < 2; ++kk) {
                const int row = lane & 15;
                const int c16 = kk * 4 + (lane >> 4);
                const int swc = c16 ^ (row & 7);
                bf16x8 a = *(const bf16x8*)&gA[k & 1][wv][row][swc * 8];
                acc[n] = __builtin_amdgcn_mfma_f32_16x16x32_bf16(a, bwk[n][kk], acc[n], 0, 0, 0);
            }
        }
    };

    #define FENCE asm volatile("" ::: "memory")

    stage(0); FENCE;

    // Phase K (private, no barriers): issue w(K) x8 then stage(K+1) x2;
    // vmcnt(2) retires s(K)+w(K), keeps s(K+1) in flight. Last phase: vmcnt(0).
    #define PHASE(K, VM)                                                   \
    {                                                                      \
        bf16x8 bwk[4][2];                                                  \
        _Pragma("unroll")                                                  \
        for (int n = 0; n < 4; ++n) {                                      \
            bwk[n][0] = ldw(K, n, 0);                                      \
            bwk[n][1] = ldw(K, n, 1);                                      \
        }                                                                  \
        FENCE;                                                             \
        if ((K) < 8) stage((K) + 1);                                       \
        FENCE;                                                             \
        asm volatile("s_waitcnt vmcnt(" #VM ")" ::: "memory");             \
        tap(K, bwk);                                                       \
        FENCE;                                                             \
    }
    PHASE(0, 2) PHASE(1, 2) PHASE(2, 2) PHASE(3, 2) PHASE(4, 2)
    PHASE(5, 2) PHASE(6, 2) PHASE(7, 2) PHASE(8, 0)
    #undef PHASE
    #undef FENCE

    // epilogue: D lane layout col = lane&15, row = (lane>>4)*4 + j within each
    // 16x16 tile; wave's rows = base + wv*16 + ... ; col-block n.
    const int orow = base + wv * 16 + (lane >> 4) * 4;
    #pragma unroll
    for (int n = 0; n < 4; ++n) {
        const int c = n * 16 + (lane & 15);
        #pragma unroll
        for (int j = 0; j < 4; ++j) {
            const int r = orow + j;
            if (r < NV) {
                float v = acc[n][j] + bv[n];
                if (LAYER == 1) {
                    bfout[r * 64 + c] = f2bf(fmaxf(v, 0.f));
                } else {
                    fout[r * 64 + c] = v + resid[r * 64 + c];
                }
            }
        }
    }
}

extern "C" void kernel_launch(void* const* d_in, const int* in_sizes, int n_in,
                              void* d_out, int out_size, void* d_ws, size_t ws_size,
                              hipStream_t stream) {
    const float* lv  = (const float*)d_in[0];
    const int*   nbr = (const int*)d_in[1];
    const float* w1  = (const float*)d_in[2];
    const float* b1  = (const float*)d_in[3];
    const float* w2  = (const float*)d_in[4];
    const float* b2  = (const float*)d_in[5];
    float* out = (float*)d_out;

    // workspace layout (needs ~73.4 MiB)
    char* ws = (char*)d_ws;
    unsigned short* xbf0 = (unsigned short*)ws;                // 38,400,000 B: bf16 relu(lv)
    unsigned short* xbf1 = (unsigned short*)(ws + 38400000);   // 38,400,000 B: bf16 relu(y1)
    unsigned short* wt1  = (unsigned short*)(ws + 76800000);   // 73,728 B
    unsigned short* wt2  = (unsigned short*)(ws + 76873728);   // 73,728 B

    const int n4blk = (NV * NF / 4 + 255) / 256;               // 18750
    prep_kernel<<<18 + n4blk, 256, 0, stream>>>(lv, w1, w2, xbf0, wt1, wt2);
    conv_kernel<1><<<NBLK, 256, 0, stream>>>(xbf0, nbr, wt1, b1, nullptr, xbf1, nullptr);
    conv_kernel<2><<<NBLK, 256, 0, stream>>>(xbf1, nbr, wt2, b2, lv, nullptr, out);
}